// Round 2
// baseline (168.097 us; speedup 1.0000x reference)
//
#include <hip/hip_runtime.h>

// PolylineEncoder: h = relu(X@W1+b1); feat = h@W2+b2; masked max over N=64 points.
// B=32 P=512 N=64 C=9 H=128.  Block = 2 polylines (128 points), grid 8192.
// GEMMs computed transposed (F^T = W2^T * H^T) so MFMA C-layout (4 consecutive
// rows per lane) packs straight into layer-2's K-contiguous B-operand layout.
// Round 2: X loaded straight into B-frags from global (no staging phase),
// pool reduced via shfl_xor (no P buffer), one barrier total, packed bf16 cvt.

using bf16x8 = __attribute__((ext_vector_type(8))) short;
using f32x4  = __attribute__((ext_vector_type(4))) float;

#define MFMA_BF16(A,B,C) __builtin_amdgcn_mfma_f32_16x16x32_bf16((A),(B),(C),0,0,0)

__device__ __forceinline__ unsigned short f2bf(float f) {
  union { float f; unsigned int u; } v; v.f = f;
  unsigned int r = v.u + 0x7fffu + ((v.u >> 16) & 1u);  // RNE
  return (unsigned short)(r >> 16);
}

// pack two floats to bf16x2 (round-half-up: +0x8000 then take hi16) via v_perm
__device__ __forceinline__ unsigned int pack_bf2(float a, float b) {
  union { float f; unsigned int u; } ua, ub; ua.f = a; ub.f = b;
  return __builtin_amdgcn_perm(ub.u + 0x8000u, ua.u + 0x8000u, 0x07060302u);
}

// ---------- prep: weight conversion + mask dtype sniff ----------
// ws layout: w1t bf16 [128][40] @0 (10240B) | w2t bf16 [128][136] @10240 (34816B) | flag @45056
__global__ void prep_kernel(const float* __restrict__ W1, const float* __restrict__ W2,
                            const void* __restrict__ mask,
                            unsigned short* __restrict__ w1t, unsigned short* __restrict__ w2t,
                            int* __restrict__ flag) {
  int b = blockIdx.x, t = threadIdx.x;
  if (b < 68) {                       // W2T[d][h] (pad h to 136)
    int idx = b * 256 + t;
    if (idx < 128 * 136) {
      int d = idx / 136, h = idx - d * 136;
      float v = (h < 128) ? W2[h * 128 + d] : 0.f;
      w2t[idx] = f2bf(v);
    }
  } else if (b < 88) {                // W1T[h][c] (pad c 9->40)
    int idx = (b - 68) * 256 + t;
    if (idx < 128 * 40) {
      int h = idx / 40, c = idx - h * 40;
      float v = (c < 9) ? W1[c * 128 + h] : 0.f;
      w1t[idx] = f2bf(v);
    }
  } else {                            // mask storage sniff over 4096 bytes
    __shared__ int cnt;
    if (t == 0) cnt = 0;
    __syncthreads();
    const unsigned char* mb = (const unsigned char*)mask;
    int local = 0;
    for (int i = t * 16; i < t * 16 + 16; i++) local += (mb[i] != 0) ? 1 : 0;
    atomicAdd(&cnt, local);
    __syncthreads();
    // ~90% valid: uint8 storage -> ~3686 nonzero bytes; int32/fp32 -> far fewer
    if (t == 0) *flag = (cnt > 2800) ? 1 : 0;   // 1 = byte-wise mask
  }
}

// ---------- main ----------
__global__ __launch_bounds__(256, 4) void poly_main_k(
    const float* __restrict__ X, const void* __restrict__ mask,
    const float* __restrict__ b1g, const float* __restrict__ b2g,
    const unsigned short* __restrict__ w1t, const unsigned short* __restrict__ w2t,
    const int* __restrict__ flagp, float* __restrict__ out)
{
  __shared__ __align__(16) unsigned short Hb[128 * 136];  // H^T as [m][h+8pad], 34816 B

  const int tid  = threadIdx.x;
  const int lane = tid & 63;
  const int w    = tid >> 6;
  const int wr   = w >> 1, wc = w & 1;     // wave grid 2x2: wr = h/d half, wc = polyline
  const int li   = lane & 15, q = lane >> 4;

  // ---- per-lane mask (additive -4e9), loaded straight from global ----
  float mf[4];
  {
    int flag = *flagp;
    long long mbase = (long long)blockIdx.x * 128 + wc * 64 + li;
    if (flag) {
      const unsigned char* mp = (const unsigned char*)mask;
      #pragma unroll
      for (int tm = 0; tm < 4; tm++) mf[tm] = mp[mbase + tm * 16] ? 0.f : -4e9f;
    } else {
      const int* mp = (const int*)mask;
      #pragma unroll
      for (int tm = 0; tm < 4; tm++) mf[tm] = mp[mbase + tm * 16] ? 0.f : -4e9f;
    }
  }

  // ---- layer-1 B-frags: X^T direct from global. k = q*8+j; only c<9 nonzero ----
  bf16x8 bx[4];
  {
    const float* xb = X + (long long)blockIdx.x * (128 * 9);
    #pragma unroll
    for (int tm = 0; tm < 4; tm++) {
      int m = wc * 64 + tm * 16 + li;
      const float* xr = xb + m * 9;
      union { bf16x8 v; unsigned int u[4]; } uu;
      uu.u[0] = uu.u[1] = uu.u[2] = uu.u[3] = 0u;
      if (q == 0) {
        uu.u[0] = pack_bf2(xr[0], xr[1]);
        uu.u[1] = pack_bf2(xr[2], xr[3]);
        uu.u[2] = pack_bf2(xr[4], xr[5]);
        uu.u[3] = pack_bf2(xr[6], xr[7]);
      } else if (q == 1) {
        uu.u[0] = pack_bf2(xr[8], 0.f);
      }
      bx[tm] = uu.v;
    }
  }

  // ---- layer 1: D1[h][m] = W1T(A, global/L1) x X^T(B, regs), K=32 ----
  f32x4 acc1[4][4];
  #pragma unroll
  for (int a = 0; a < 4; a++)
    #pragma unroll
    for (int b = 0; b < 4; b++) acc1[a][b] = f32x4{0.f, 0.f, 0.f, 0.f};
  {
    bf16x8 af[4];
    #pragma unroll
    for (int th = 0; th < 4; th++)
      af[th] = *(const bf16x8*)(w1t + (wr * 64 + th * 16 + li) * 40 + q * 8);
    #pragma unroll
    for (int th = 0; th < 4; th++)
      #pragma unroll
      for (int tm = 0; tm < 4; tm++)
        acc1[th][tm] = MFMA_BF16(af[th], bx[tm], acc1[th][tm]);
  }

  // ---- epilogue 1: +b1, relu, packed bf16, H^T[m][h] as b64 ----
  #pragma unroll
  for (int th = 0; th < 4; th++) {
    f32x4 bv = *(const f32x4*)(b1g + wr * 64 + th * 16 + q * 4);
    #pragma unroll
    for (int tm = 0; tm < 4; tm++) {
      int m = wc * 64 + tm * 16 + li;
      float v0 = fmaxf(acc1[th][tm][0] + bv[0], 0.f);
      float v1 = fmaxf(acc1[th][tm][1] + bv[1], 0.f);
      float v2 = fmaxf(acc1[th][tm][2] + bv[2], 0.f);
      float v3 = fmaxf(acc1[th][tm][3] + bv[3], 0.f);
      uint2 hv;
      hv.x = pack_bf2(v0, v1);
      hv.y = pack_bf2(v2, v3);
      *(uint2*)(Hb + m * 136 + wr * 64 + th * 16 + q * 4) = hv;
    }
  }
  __syncthreads();   // the only barrier

  // ---- layer 2: D2[d][m] = W2T(A, global/L1) x H^T(B, LDS), K=128 ----
  f32x4 acc2[4][4];
  #pragma unroll
  for (int a = 0; a < 4; a++)
    #pragma unroll
    for (int b = 0; b < 4; b++) acc2[a][b] = f32x4{0.f, 0.f, 0.f, 0.f};
  #pragma unroll
  for (int ks = 0; ks < 4; ks++) {
    bf16x8 af[4], bf[4];
    #pragma unroll
    for (int td = 0; td < 4; td++)
      af[td] = *(const bf16x8*)(w2t + (wr * 64 + td * 16 + li) * 136 + ks * 32 + q * 8);
    #pragma unroll
    for (int tm = 0; tm < 4; tm++)
      bf[tm] = *(const bf16x8*)(Hb + (wc * 64 + tm * 16 + li) * 136 + ks * 32 + q * 8);
    #pragma unroll
    for (int td = 0; td < 4; td++)
      #pragma unroll
      for (int tm = 0; tm < 4; tm++)
        acc2[td][tm] = MFMA_BF16(af[td], bf[tm], acc2[td][tm]);
  }

  // ---- pool over the 4 m-tiles (additive mask; bias after max) ----
  f32x4 pooled[4];
  #pragma unroll
  for (int td = 0; td < 4; td++) {
    f32x4 bv = *(const f32x4*)(b2g + wr * 64 + td * 16 + q * 4);
    #pragma unroll
    for (int r = 0; r < 4; r++) {
      float v0 = acc2[td][0][r] + mf[0];
      float v1 = acc2[td][1][r] + mf[1];
      float v2 = acc2[td][2][r] + mf[2];
      float v3 = acc2[td][3][r] + mf[3];
      pooled[td][r] = fmaxf(fmaxf(v0, v1), fmaxf(v2, v3)) + bv[r];
    }
  }

  // ---- reduce over the 16 li-lanes with shfl_xor (masks <16 stay in q-group) ----
  #pragma unroll
  for (int s = 8; s >= 1; s >>= 1) {
    #pragma unroll
    for (int td = 0; td < 4; td++) {
      #pragma unroll
      for (int r = 0; r < 4; r++) {
        float o = __shfl_xor(pooled[td][r], s, 64);
        pooled[td][r] = fmaxf(pooled[td][r], o);
      }
    }
  }

  // ---- li==0 lanes store; all-invalid polyline -> 0 ----
  if (li == 0) {
    long long poly = (long long)blockIdx.x * 2 + wc;
    #pragma unroll
    for (int td = 0; td < 4; td++) {
      f32x4 v = pooled[td];
      #pragma unroll
      for (int r = 0; r < 4; r++) if (v[r] < -1e8f) v[r] = 0.f;
      *(f32x4*)(out + poly * 128 + wr * 64 + td * 16 + q * 4) = v;
    }
  }
}

extern "C" void kernel_launch(void* const* d_in, const int* in_sizes, int n_in,
                              void* d_out, int out_size, void* d_ws, size_t ws_size,
                              hipStream_t stream) {
  const float* X    = (const float*)d_in[0];
  const void*  mask = d_in[1];
  const float* W1   = (const float*)d_in[2];
  const float* b1   = (const float*)d_in[3];
  const float* W2   = (const float*)d_in[4];
  const float* b2   = (const float*)d_in[5];
  float* out = (float*)d_out;

  unsigned short* w1t = (unsigned short*)d_ws;
  unsigned short* w2t = w1t + 128 * 40;
  int* flag = (int*)((char*)d_ws + 45056);

  prep_kernel<<<89, 256, 0, stream>>>(W1, W2, mask, w1t, w2t, flag);
  poly_main_k<<<8192, 256, 0, stream>>>(X, mask, b1, b2, w1t, w2t, flag, out);
}

// Round 4
// 143.075 us; speedup vs baseline: 1.1749x; 1.1749x over previous
//
#include <hip/hip_runtime.h>

// PolylineEncoder: h = relu(X@W1+b1); feat = h@W2+b2; masked max over N=64 points.
// B=32 P=512 N=64 C=9 H=128.  Block = 2 polylines (128 points), grid 8192.
// R4 = R3 structure with layer-1 reverted to the VERIFIED 16x16x32 MFMA
// (the 16x16x16 fragment layout was unmeasured on gfx950 and wrong).
// Weights pre-swizzled into frag order (1 coalesced 16B/lane load per frag),
// X staged raw f32 via b128, mask as ballot bitmask, output via LDS transpose.

using bf16x8 = __attribute__((ext_vector_type(8))) short;
using f32x4  = __attribute__((ext_vector_type(4))) float;

#define MFMA32(A,B,C) __builtin_amdgcn_mfma_f32_16x16x32_bf16((A),(B),(C),0,0,0)

__device__ __forceinline__ unsigned short f2bf(float f) {
  union { float f; unsigned int u; } v; v.f = f;
  unsigned int r = v.u + 0x7fffu + ((v.u >> 16) & 1u);  // RNE
  return (unsigned short)(r >> 16);
}

// pack two floats to bf16x2 (round-half-up) via v_perm: 3 VALU per 2 elems
__device__ __forceinline__ unsigned int pack_bf2(float a, float b) {
  union { float f; unsigned int u; } ua, ub; ua.f = a; ub.f = b;
  return __builtin_amdgcn_perm(ub.u + 0x8000u, ua.u + 0x8000u, 0x07060302u);
}

// ---------------- prep1: mask sniff + frag-swizzled weights ----------------
// ws: w1sw @0 (8KB) | w2sw @8192 (32KB) | flag @40960 | bits @49152 (128KB)
__global__ void prep1(const float* __restrict__ W1, const float* __restrict__ W2,
                      const void* __restrict__ mask,
                      unsigned short* __restrict__ w1sw, unsigned short* __restrict__ w2sw,
                      int* __restrict__ flag) {
  int b = blockIdx.x, t = threadIdx.x;
  if (b == 0) {                      // mask storage sniff over 4096 bytes
    __shared__ int cnt;
    if (t == 0) cnt = 0;
    __syncthreads();
    const unsigned char* mb = (const unsigned char*)mask;
    int local = 0;
    for (int i = t * 16; i < t * 16 + 16; i++) local += (mb[i] != 0) ? 1 : 0;
    atomicAdd(&cnt, local);
    __syncthreads();
    if (t == 0) *flag = (cnt > 2800) ? 1 : 0;   // 1 = byte-wise mask, else int32-wise
  } else if (b <= 2) {
    // w1 A-frags (16x16x32): entry e = (wr*4+th)*64 + lane; h=(e>>6)*16+(lane&15)
    int e = (b - 1) * 256 + t;       // 512 entries x 8 halves = 8KB
    int lane = e & 63, grp = e >> 6;
    int li = lane & 15, q = lane >> 4;
    int h = grp * 16 + li;
    int c0 = q * 8;
    #pragma unroll
    for (int j = 0; j < 8; j++) {
      int c = c0 + j;
      w1sw[e * 8 + j] = f2bf((c < 9) ? W1[c * 128 + h] : 0.f);
    }
  } else {
    // w2 A-frags (16x16x32): entry e = (wr*16+ks*4+td)*64 + lane; 8 halves each
    int e = (b - 3) * 256 + t;       // 2048 entries x 8 halves = 32KB
    if (e < 2048) {
      int lane = e & 63, grp = e >> 6;
      int wr = grp >> 4, sub = grp & 15;
      int ks = sub >> 2, td = sub & 3;
      int li = lane & 15, q = lane >> 4;
      int d = wr * 64 + td * 16 + li;
      int h0 = ks * 32 + q * 8;
      #pragma unroll
      for (int j = 0; j < 8; j++)
        w2sw[e * 8 + j] = f2bf(W2[(h0 + j) * 128 + d]);
    }
  }
}

// ---------------- prep2: mask -> bitmask (1 bit/point, u64 per polyline) ----
__global__ void prep2(const void* __restrict__ mask, const int* __restrict__ flagp,
                      unsigned long long* __restrict__ bits) {
  int gid = blockIdx.x * 256 + threadIdx.x;
  int flag = *flagp;
  bool v;
  if (flag) v = ((const unsigned char*)mask)[gid] != 0;
  else      v = ((const int*)mask)[gid] != 0;
  unsigned long long bm = __ballot(v);
  if ((threadIdx.x & 63) == 0)
    bits[blockIdx.x * 4 + (threadIdx.x >> 6)] = bm;
}

// ---------------- main ----------------
__global__ __launch_bounds__(256, 4) void poly_main_k(
    const float* __restrict__ X, const void* __restrict__ mask,
    const float* __restrict__ b1g, const float* __restrict__ b2g,
    const unsigned short* __restrict__ w1sw, const unsigned short* __restrict__ w2sw,
    const int* __restrict__ flagp, const unsigned long long* __restrict__ bits,
    int use_bits, float* __restrict__ out)
{
  __shared__ __align__(16) float Xs[1152];                // raw X block, 4608 B
  __shared__ __align__(16) unsigned short Hb[128 * 136];  // H^T [m][h+8pad]; P reuses it

  const int tid  = threadIdx.x;
  const int lane = tid & 63;
  const int w    = tid >> 6;
  const int wr   = w >> 1, wc = w & 1;   // wr = h/d half, wc = polyline in block
  const int li   = lane & 15, q = lane >> 4;

  // ---- mask: one uniform u64 per wave (bit per point) ----
  float mf[4];
  if (use_bits) {
    unsigned long long bm = bits[(long long)blockIdx.x * 2 + wc];
    #pragma unroll
    for (int tm = 0; tm < 4; tm++)
      mf[tm] = ((bm >> (tm * 16 + li)) & 1ull) ? 0.f : -4e9f;
  } else {
    int flag = *flagp;
    long long mb = (long long)blockIdx.x * 128 + wc * 64 + li;
    if (flag) {
      const unsigned char* mp = (const unsigned char*)mask;
      #pragma unroll
      for (int tm = 0; tm < 4; tm++) mf[tm] = mp[mb + tm * 16] ? 0.f : -4e9f;
    } else {
      const int* mp = (const int*)mask;
      #pragma unroll
      for (int tm = 0; tm < 4; tm++) mf[tm] = mp[mb + tm * 16] ? 0.f : -4e9f;
    }
  }

  // ---- stage X: 288 float4 coalesced global -> LDS b128, zero remap math ----
  {
    const f32x4* xg = (const f32x4*)(X + (long long)blockIdx.x * 1152);
    f32x4* xl = (f32x4*)Xs;
    xl[tid] = xg[tid];
    if (tid < 32) xl[tid + 256] = xg[tid + 256];
  }
  __syncthreads();  // b0

  // ---- layer-1 B-frags from Xs: B[m][k], k=q*8+j, only c<9 nonzero ----
  bf16x8 bx[4];
  #pragma unroll
  for (int tm = 0; tm < 4; tm++) {
    int m = wc * 64 + tm * 16 + li;
    const float* xr = Xs + m * 9;
    union { bf16x8 v; unsigned int u[4]; } uu;
    uu.u[0] = uu.u[1] = uu.u[2] = uu.u[3] = 0u;
    if (q == 0) {
      uu.u[0] = pack_bf2(xr[0], xr[1]); uu.u[1] = pack_bf2(xr[2], xr[3]);
      uu.u[2] = pack_bf2(xr[4], xr[5]); uu.u[3] = pack_bf2(xr[6], xr[7]);
    } else if (q == 1) {
      uu.u[0] = pack_bf2(xr[8], 0.f);
    }
    bx[tm] = uu.v;
  }

  // ---- layer 1: D1[h][m] = W1frag(A, coalesced global) x X^T(B, regs), K=32 ----
  f32x4 acc1[4][4];
  #pragma unroll
  for (int a = 0; a < 4; a++)
    #pragma unroll
    for (int b = 0; b < 4; b++) acc1[a][b] = f32x4{0.f, 0.f, 0.f, 0.f};
  {
    bf16x8 a1[4];
    #pragma unroll
    for (int th = 0; th < 4; th++)
      a1[th] = *(const bf16x8*)(w1sw + ((wr * 4 + th) * 64 + lane) * 8);
    #pragma unroll
    for (int th = 0; th < 4; th++)
      #pragma unroll
      for (int tm = 0; tm < 4; tm++)
        acc1[th][tm] = MFMA32(a1[th], bx[tm], acc1[th][tm]);
  }

  // ---- epilogue 1: +b1, relu, pack, H^T[m][h] ----
  #pragma unroll
  for (int th = 0; th < 4; th++) {
    f32x4 bv = *(const f32x4*)(b1g + wr * 64 + th * 16 + q * 4);
    #pragma unroll
    for (int tm = 0; tm < 4; tm++) {
      int m = wc * 64 + tm * 16 + li;
      float v0 = fmaxf(acc1[th][tm][0] + bv[0], 0.f);
      float v1 = fmaxf(acc1[th][tm][1] + bv[1], 0.f);
      float v2 = fmaxf(acc1[th][tm][2] + bv[2], 0.f);
      float v3 = fmaxf(acc1[th][tm][3] + bv[3], 0.f);
      uint2 hv;
      hv.x = pack_bf2(v0, v1);
      hv.y = pack_bf2(v2, v3);
      *(uint2*)(Hb + m * 136 + wr * 64 + th * 16 + q * 4) = hv;
    }
  }
  __syncthreads();  // b1: Hb ready

  // ---- layer 2: D2[d][m] = W2frag(A, coalesced global) x H^T(B, LDS), K=128 ----
  f32x4 acc2[4][4];
  #pragma unroll
  for (int a = 0; a < 4; a++)
    #pragma unroll
    for (int b = 0; b < 4; b++) acc2[a][b] = f32x4{0.f, 0.f, 0.f, 0.f};
  #pragma unroll
  for (int ks = 0; ks < 4; ks++) {
    bf16x8 a2[4], bb[4];
    #pragma unroll
    for (int td = 0; td < 4; td++)
      a2[td] = *(const bf16x8*)(w2sw + (((wr * 16 + ks * 4 + td) * 64) + lane) * 8);
    #pragma unroll
    for (int tm = 0; tm < 4; tm++)
      bb[tm] = *(const bf16x8*)(Hb + (wc * 64 + tm * 16 + li) * 136 + ks * 32 + q * 8);
    #pragma unroll
    for (int td = 0; td < 4; td++)
      #pragma unroll
      for (int tm = 0; tm < 4; tm++)
        acc2[td][tm] = MFMA32(a2[td], bb[tm], acc2[td][tm]);
  }

  // ---- pool over 4 m-tiles in-reg (additive mask, bias after max) ----
  f32x4 pooled[4];
  #pragma unroll
  for (int td = 0; td < 4; td++) {
    f32x4 bv = *(const f32x4*)(b2g + wr * 64 + td * 16 + q * 4);
    #pragma unroll
    for (int r = 0; r < 4; r++) {
      float v0 = acc2[td][0][r] + mf[0];
      float v1 = acc2[td][1][r] + mf[1];
      float v2 = acc2[td][2][r] + mf[2];
      float v3 = acc2[td][3][r] + mf[3];
      pooled[td][r] = fmaxf(fmaxf(v0, v1), fmaxf(v2, v3)) + bv[r];
    }
  }

  __syncthreads();  // b2: all Hb reads done -> safe to reuse Hb as P
  // P[wc][li][d] f32, d-stride 1, li-stride 132 (pad breaks 2^k bank stride)
  float* P = (float*)Hb;
  #pragma unroll
  for (int td = 0; td < 4; td++)
    *(f32x4*)(P + (wc * 16 + li) * 132 + wr * 64 + td * 16 + q * 4) = pooled[td];
  __syncthreads();  // b3: P ready

  // ---- final: reduce 16 li-partials per (poly,d), coalesced full-line store ----
  {
    int p = tid >> 7, d = tid & 127;
    const float* Pp = P + p * (16 * 132) + d;
    float v = Pp[0];
    #pragma unroll
    for (int j = 1; j < 16; j++) v = fmaxf(v, Pp[j * 132]);
    if (v < -1e8f) v = 0.f;
    out[(long long)blockIdx.x * 256 + tid] = v;
  }
}

extern "C" void kernel_launch(void* const* d_in, const int* in_sizes, int n_in,
                              void* d_out, int out_size, void* d_ws, size_t ws_size,
                              hipStream_t stream) {
  const float* X    = (const float*)d_in[0];
  const void*  mask = d_in[1];
  const float* W1   = (const float*)d_in[2];
  const float* b1   = (const float*)d_in[3];
  const float* W2   = (const float*)d_in[4];
  const float* b2   = (const float*)d_in[5];
  float* out = (float*)d_out;

  unsigned short* w1sw = (unsigned short*)d_ws;
  unsigned short* w2sw = (unsigned short*)((char*)d_ws + 8192);
  int* flag            = (int*)((char*)d_ws + 40960);
  unsigned long long* bits = (unsigned long long*)((char*)d_ws + 49152);
  int use_bits = (ws_size >= (size_t)(49152 + 131072)) ? 1 : 0;

  prep1<<<11, 256, 0, stream>>>(W1, W2, mask, w1sw, w2sw, flag);
  if (use_bits) prep2<<<4096, 256, 0, stream>>>(mask, flag, bits);
  poly_main_k<<<8192, 256, 0, stream>>>(X, mask, b1, b2, w1sw, w2sw, flag, bits,
                                        use_bits, out);
}